// Round 2
// baseline (271.359 us; speedup 1.0000x reference)
//
#include <hip/hip_runtime.h>
#include <hip/hip_bf16.h>
#include <stdint.h>

#define BQ   8
#define SEQ  2048
#define EMB  512

typedef __attribute__((ext_vector_type(8))) short short8;
typedef __attribute__((ext_vector_type(4))) float floatx4;
typedef __attribute__((ext_vector_type(4))) unsigned short ushort4_t;
typedef __hip_bfloat16 bf16;

__device__ __forceinline__ unsigned short f2bf(float f) {
    union { bf16 h; unsigned short u; } c;
    c.h = __float2bfloat16(f);
    return c.u;
}

// ---------------- fp32 -> bf16 convert (optionally scaled) ----------------
__global__ __launch_bounds__(256) void cvt_f32_to_bf16(
    const float* __restrict__ in, bf16* __restrict__ out, long n4, float scale)
{
    long i = (long)blockIdx.x * 256 + threadIdx.x;
    if (i >= n4) return;
    floatx4 v = *(const floatx4*)(in + i * 4);
    ushort4_t o;
    o.x = f2bf(v.x * scale);
    o.y = f2bf(v.y * scale);
    o.z = f2bf(v.z * scale);
    o.w = f2bf(v.w * scale);
    *(ushort4_t*)((unsigned short*)out + i * 4) = o;
}

// ---------------- mask(bool, stored as int32 OR uint8) -> f32 bias --------
__global__ __launch_bounds__(256) void mask_to_bias(
    const void* __restrict__ mraw, float* __restrict__ bias)
{
    __shared__ int bad;
    int tid = threadIdx.x;
    if (tid == 0) bad = 0;
    __syncthreads();
    const int* mi = (const int*)mraw;
    int local = 0;
    for (int i = tid; i < 4096; i += 256) {
        unsigned v = (unsigned)mi[i];
        if (v > 1u) local = 1;
    }
    if (local) atomicOr(&bad, 1);
    __syncthreads();
    bool as_int = (bad == 0);
    const unsigned char* mb = (const unsigned char*)mraw;
    for (int i = tid; i < BQ * SEQ; i += 256) {
        int mv = as_int ? mi[i] : (int)mb[i];
        bias[i] = mv ? -1e9f : 0.0f;
    }
}

// ---------------- B^T GEMM: C[m][n] = sum_k A[m][k]*Bt[n][k] --------------
// 128x128 tile, 4 waves, 16x16x32 bf16 MFMA, BK=32, global_load_lds staging.
enum { EPI_BF16 = 0, EPI_TRANS = 1 };

template <int EPI>
__global__ __launch_bounds__(256) void gemm_bt(
    const bf16* __restrict__ A, const bf16* __restrict__ Bt,
    void* __restrict__ C, int Ncols, int K)
{
    __shared__ __attribute__((aligned(16))) bf16 lA[128 * 32];
    __shared__ __attribute__((aligned(16))) bf16 lB[128 * 32];

    const int tid  = threadIdx.x;
    const int lane = tid & 63;
    const int wv   = tid >> 6;
    const int wr   = wv >> 1, wc = wv & 1;
    const long brow = (long)blockIdx.y * 128;
    const long bcol = (long)blockIdx.x * 128;

    floatx4 acc[4][4];
#pragma unroll
    for (int m = 0; m < 4; m++)
#pragma unroll
        for (int n = 0; n < 4; n++) acc[m][n] = (floatx4)0.0f;

    const int hi  = lane >> 4;
    const int r16 = lane & 15;

    for (int kt = 0; kt < K; kt += 32) {
#pragma unroll
        for (int it = 0; it < 2; ++it) {
            int c = it * 256 + tid;
            const bf16* src = A + (brow + (c >> 2)) * (long)K + kt + (c & 3) * 8;
            __builtin_amdgcn_global_load_lds(
                (const __attribute__((address_space(1))) void*)src,
                (__attribute__((address_space(3))) void*)(&lA[(it * 256 + wv * 64) * 8]),
                16, 0, 0);
        }
#pragma unroll
        for (int it = 0; it < 2; ++it) {
            int c = it * 256 + tid;
            const bf16* src = Bt + (bcol + (c >> 2)) * (long)K + kt + (c & 3) * 8;
            __builtin_amdgcn_global_load_lds(
                (const __attribute__((address_space(1))) void*)src,
                (__attribute__((address_space(3))) void*)(&lB[(it * 256 + wv * 64) * 8]),
                16, 0, 0);
        }
        __syncthreads();

        short8 af[4], bfr[4];
#pragma unroll
        for (int m = 0; m < 4; m++)
            af[m] = *(const short8*)&lA[(wr * 64 + m * 16 + r16) * 32 + hi * 8];
#pragma unroll
        for (int n = 0; n < 4; n++)
            bfr[n] = *(const short8*)&lB[(wc * 64 + n * 16 + r16) * 32 + hi * 8];
#pragma unroll
        for (int m = 0; m < 4; m++)
#pragma unroll
            for (int n = 0; n < 4; n++)
                acc[m][n] = __builtin_amdgcn_mfma_f32_16x16x32_bf16(
                    af[m], bfr[n], acc[m][n], 0, 0, 0);
        __syncthreads();
    }

#pragma unroll
    for (int m = 0; m < 4; m++) {
#pragma unroll
        for (int n = 0; n < 4; n++) {
#pragma unroll
            for (int j = 0; j < 4; j++) {
                long row = brow + wr * 64 + m * 16 + hi * 4 + j;
                long col = bcol + wc * 64 + n * 16 + r16;
                float v = acc[m][n][j];
                if constexpr (EPI == EPI_BF16) {
                    ((bf16*)C)[row * (long)Ncols + col] = __float2bfloat16(v);
                } else { // EPI_TRANS: Vt[b][e][n]
                    long bb = row >> 11, t = row & 2047;
                    ((bf16*)C)[(bb * EMB + col) * SEQ + t] = __float2bfloat16(v);
                }
            }
        }
    }
}

// ---------------- fused flash attention -----------------------------------
// 256 blocks (b = bid&7 for XCD locality, qt = bid>>3), 4 waves, Q-tile 64.
// Q in regs; K dbl-buffered LDS (XOR-swizzled); V from global Vt into regs;
// P via LDS; defer-max online softmax.
__global__ __launch_bounds__(256, 1) void flash_attn(
    const bf16* __restrict__ Q, const bf16* __restrict__ K,
    const bf16* __restrict__ Vt, const float* __restrict__ bias,
    float* __restrict__ out)
{
    __shared__ __attribute__((aligned(16))) bf16 Klds[2][32 * 512];
    __shared__ __attribute__((aligned(16))) bf16 Plds[64 * 32];
    __shared__ float biasLds[SEQ];
    __shared__ float scaleLds[64];
    __shared__ float lLds[64];
    __shared__ int flagLds[2];

    const int tid  = threadIdx.x;
    const int lane = tid & 63;
    const int wv   = tid >> 6;          // 0..3
    const int r16  = lane & 15, hi = lane >> 4;

    const int bid = blockIdx.x;
    const int b   = bid & 7;            // batch -> XCD
    const int qt  = bid >> 3;           // 0..31
    const long q0 = (long)qt * 64;

    const bf16* Qb = Q  + (long)b * SEQ * EMB;
    const bf16* Kb = K  + (long)b * SEQ * EMB;
    const bf16* Vb = Vt + (long)b * EMB * SEQ;
    const float* biasb = bias + (long)b * SEQ;

    for (int i = tid; i < SEQ / 4; i += 256)
        *(floatx4*)&biasLds[i * 4] = *(const floatx4*)&biasb[i * 4];
    if (tid < 2) flagLds[tid] = 0;

    // Q fragments: wave rows q0 + wv*16 + r16, 16 K-steps of 32
    short8 qf[16];
    {
        const bf16* qrow = Qb + (q0 + wv * 16 + r16) * EMB;
#pragma unroll
        for (int ks = 0; ks < 16; ks++)
            qf[ks] = *(const short8*)(qrow + ks * 32 + hi * 8);
    }

    floatx4 oacc[4][8];
#pragma unroll
    for (int mf = 0; mf < 4; mf++)
#pragma unroll
        for (int nf = 0; nf < 8; nf++) oacc[mf][nf] = (floatx4)0.f;

    float m_r[4], l_r[4];
#pragma unroll
    for (int j = 0; j < 4; j++) { m_r[j] = -3e38f; l_r[j] = 0.f; }

    auto stageK = [&](int buf, int t) {
#pragma unroll
        for (int c = 0; c < 8; c++) {
            int row = wv * 8 + c;
            // inverse-swizzled source: lds[row][chunk d] = global[row][d ^ (row&7)]
            const bf16* src = Kb + ((long)t * 32 + row) * EMB + (lane ^ (row & 7)) * 8;
            __builtin_amdgcn_global_load_lds(
                (const __attribute__((address_space(1))) void*)src,
                (__attribute__((address_space(3))) void*)(&Klds[buf][row * EMB]),
                16, 0, 0);
        }
    };

    stageK(0, 0);
    __syncthreads();

    const int NT = SEQ / 32;   // 64
    for (int t = 0; t < NT; t++) {
        const int cur = t & 1;

        // V fragments for tile t (own 128 cols, straight from global Vt)
        short8 vf[8];
#pragma unroll
        for (int nf = 0; nf < 8; nf++)
            vf[nf] = *(const short8*)(Vb + (long)(wv * 128 + nf * 16 + r16) * SEQ + t * 32 + hi * 8);

        if (t + 1 < NT) stageK(cur ^ 1, t + 1);

        // ---- S = Q @ K^T (swizzled LDS reads), 2 chains per acc ----
        floatx4 s0a = (floatx4)0.f, s0b = (floatx4)0.f;
        floatx4 s1a = (floatx4)0.f, s1b = (floatx4)0.f;
        const char* kbase = (const char*)&Klds[cur][0];
        const int rowb0 = r16 * 1024, rowb1 = (16 + r16) * 1024;
        const int sw = (r16 & 7);
#pragma unroll
        for (int ks = 0; ks < 16; ks += 2) {
            int c0 = ((ks * 4 + hi) ^ sw) * 16;
            short8 b00 = *(const short8*)(kbase + rowb0 + c0);
            short8 b01 = *(const short8*)(kbase + rowb1 + c0);
            s0a = __builtin_amdgcn_mfma_f32_16x16x32_bf16(qf[ks], b00, s0a, 0, 0, 0);
            s1a = __builtin_amdgcn_mfma_f32_16x16x32_bf16(qf[ks], b01, s1a, 0, 0, 0);
            int c1 = (((ks + 1) * 4 + hi) ^ sw) * 16;
            short8 b10 = *(const short8*)(kbase + rowb0 + c1);
            short8 b11 = *(const short8*)(kbase + rowb1 + c1);
            s0b = __builtin_amdgcn_mfma_f32_16x16x32_bf16(qf[ks + 1], b10, s0b, 0, 0, 0);
            s1b = __builtin_amdgcn_mfma_f32_16x16x32_bf16(qf[ks + 1], b11, s1b, 0, 0, 0);
        }
        floatx4 s0 = s0a + s0b, s1 = s1a + s1b;

        // ---- online softmax (rows = wv*16 + hi*4 + j, cols r16 / 16+r16) --
        float bias0 = biasLds[t * 32 + r16], bias1 = biasLds[t * 32 + 16 + r16];
        float sv0[4], sv1[4], tmax[4];
#pragma unroll
        for (int j = 0; j < 4; j++) {
            sv0[j] = s0[j] + bias0;
            sv1[j] = s1[j] + bias1;
            tmax[j] = fmaxf(sv0[j], sv1[j]);
        }
#pragma unroll
        for (int j = 0; j < 4; j++) {
            tmax[j] = fmaxf(tmax[j], __shfl_xor(tmax[j], 1));
            tmax[j] = fmaxf(tmax[j], __shfl_xor(tmax[j], 2));
            tmax[j] = fmaxf(tmax[j], __shfl_xor(tmax[j], 4));
            tmax[j] = fmaxf(tmax[j], __shfl_xor(tmax[j], 8));
        }
        float sc[4];
        int resc = 0;
#pragma unroll
        for (int j = 0; j < 4; j++) {
            if (tmax[j] > m_r[j] + 8.0f) {          // defer-max (T13)
                sc[j] = __expf(m_r[j] - tmax[j]);
                m_r[j] = tmax[j];
                resc = 1;
            } else sc[j] = 1.0f;
        }
        float p0[4], p1[4], rsum[4];
#pragma unroll
        for (int j = 0; j < 4; j++) {
            p0[j] = __expf(sv0[j] - m_r[j]);
            p1[j] = __expf(sv1[j] - m_r[j]);
            rsum[j] = p0[j] + p1[j];
        }
#pragma unroll
        for (int j = 0; j < 4; j++) {
            rsum[j] += __shfl_xor(rsum[j], 1);
            rsum[j] += __shfl_xor(rsum[j], 2);
            rsum[j] += __shfl_xor(rsum[j], 4);
            rsum[j] += __shfl_xor(rsum[j], 8);
            l_r[j] = l_r[j] * sc[j] + rsum[j];
        }
        unsigned short* Pp = (unsigned short*)Plds;
#pragma unroll
        for (int j = 0; j < 4; j++) {
            int row = wv * 16 + hi * 4 + j;
            Pp[row * 32 + r16]      = f2bf(p0[j]);
            Pp[row * 32 + 16 + r16] = f2bf(p1[j]);
        }
        if (r16 == 0) {
#pragma unroll
            for (int j = 0; j < 4; j++) scaleLds[wv * 16 + hi * 4 + j] = sc[j];
        }
        if (__any(resc) && lane == 0) flagLds[cur] = 1;
        if (tid == 0) flagLds[cur ^ 1] = 0;
        __syncthreads();                    // P + scales visible

        if (flagLds[cur]) {                 // rare O-rescale
#pragma unroll
            for (int mf = 0; mf < 4; mf++)
#pragma unroll
                for (int j = 0; j < 4; j++) {
                    float s = scaleLds[mf * 16 + hi * 4 + j];
#pragma unroll
                    for (int nf = 0; nf < 8; nf++) oacc[mf][nf][j] *= s;
                }
        }

        // ---- O += P @ V (A from P_lds, B from regs) ----
        short8 pa[4];
#pragma unroll
        for (int mf = 0; mf < 4; mf++)
            pa[mf] = *(const short8*)&Plds[(mf * 16 + r16) * 32 + hi * 8];
#pragma unroll
        for (int mf = 0; mf < 4; mf++)
#pragma unroll
            for (int nf = 0; nf < 8; nf++)
                oacc[mf][nf] = __builtin_amdgcn_mfma_f32_16x16x32_bf16(
                    pa[mf], vf[nf], oacc[mf][nf], 0, 0, 0);
        __syncthreads();                    // K staging drained; P reusable
    }

    if (r16 == 0) {
#pragma unroll
        for (int j = 0; j < 4; j++) lLds[wv * 16 + hi * 4 + j] = l_r[j];
    }
    __syncthreads();

    float* ob = out + ((long)b * SEQ + q0) * EMB + wv * 128;
#pragma unroll
    for (int mf = 0; mf < 4; mf++)
#pragma unroll
        for (int j = 0; j < 4; j++) {
            float inv = 1.0f / lLds[mf * 16 + hi * 4 + j];
            long rowoff = (long)(mf * 16 + hi * 4 + j) * EMB;
#pragma unroll
            for (int nf = 0; nf < 8; nf++)
                ob[rowoff + nf * 16 + r16] = oacc[mf][nf][j] * inv;
        }
}

// --------------------------------------------------------------------------
extern "C" void kernel_launch(void* const* d_in, const int* in_sizes, int n_in,
                              void* d_out, int out_size, void* d_ws, size_t ws_size,
                              hipStream_t stream)
{
    const float* feat = (const float*)d_in[0];
    const void*  mask = d_in[1];
    const float* Wq   = (const float*)d_in[2];
    const float* Wk   = (const float*)d_in[3];
    const float* Wv   = (const float*)d_in[4];
    float* out = (float*)d_out;

    const long M  = (long)BQ * SEQ;
    const long NE = M * EMB;
    const long NW = (long)EMB * EMB;

    char* ws = (char*)d_ws;
    size_t off = 0;
    auto carve = [&](size_t bytes) -> void* {
        void* p = ws + off;
        off = (off + bytes + 4095) & ~(size_t)4095;
        return p;
    };
    bf16*  Xb   = (bf16*)carve(NE * 2);
    bf16*  Wqb  = (bf16*)carve(NW * 2);
    bf16*  Wkb  = (bf16*)carve(NW * 2);
    bf16*  Wvb  = (bf16*)carve(NW * 2);
    bf16*  Qb   = (bf16*)carve(NE * 2);
    bf16*  Kb   = (bf16*)carve(NE * 2);
    bf16*  Vt   = (bf16*)carve(NE * 2);
    float* bias = (float*)carve(M * 4);
    (void)ws_size; (void)in_sizes; (void)n_in; (void)out_size;

    const float qscale = 0.04419417382415922f;  // 512^-0.5 folded into Wq

    cvt_f32_to_bf16<<<dim3((NE / 4 + 255) / 256), dim3(256), 0, stream>>>(feat, Xb, NE / 4, 1.0f);
    cvt_f32_to_bf16<<<dim3((NW / 4 + 255) / 256), dim3(256), 0, stream>>>(Wq, Wqb, NW / 4, qscale);
    cvt_f32_to_bf16<<<dim3((NW / 4 + 255) / 256), dim3(256), 0, stream>>>(Wk, Wkb, NW / 4, 1.0f);
    cvt_f32_to_bf16<<<dim3((NW / 4 + 255) / 256), dim3(256), 0, stream>>>(Wv, Wvb, NW / 4, 1.0f);
    mask_to_bias<<<dim3(1), dim3(256), 0, stream>>>(mask, bias);

    gemm_bt<EPI_BF16><<<dim3(4, 128), dim3(256), 0, stream>>>(Xb, Wqb, Qb, EMB, EMB);
    gemm_bt<EPI_BF16><<<dim3(4, 128), dim3(256), 0, stream>>>(Xb, Wkb, Kb, EMB, EMB);
    gemm_bt<EPI_TRANS><<<dim3(4, 128), dim3(256), 0, stream>>>(Xb, Wvb, Vt, EMB, EMB);

    flash_attn<<<dim3(256), dim3(256), 0, stream>>>(Qb, Kb, Vt, bias, out);
}